// Round 1
// baseline (533.909 us; speedup 1.0000x reference)
//
#include <hip/hip_runtime.h>

// JPEG decode, fully fused: dequant + separable 8x8 IDCT + unblock +
// 2x chroma upsample + YCbCr->RGB + clip/255, one kernel, no workspace.
//
// Fixed problem size from setup_inputs(): B=8, H=2048, W=2048.
// Tile: 16 rows x 128 cols of output per 256-thread workgroup.
//   -> 32 Y blocks (2x16), 8 Cb blocks, 8 Cr blocks per tile.

#define H 2048
#define W 2048
#define YBLK_COLS (W / 8)     // 256
#define CBLK_COLS (W / 16)    // 128

__global__ __launch_bounds__(256) void jpeg_decode_kernel(
    const float* __restrict__ yg,
    const float* __restrict__ cbg,
    const float* __restrict__ crg,
    const float* __restrict__ y_table,
    const float* __restrict__ c_table,
    const float* __restrict__ alpha,
    const float* __restrict__ dct,
    const float* __restrict__ shiftp,
    const float* __restrict__ matp,
    const int* __restrict__ factor_p,
    float* __restrict__ out)
{
    __shared__ float qY[64];        // y_table*factor*alpha
    __shared__ float qC[64];        // c_table*factor*alpha
    __shared__ float cosT[64];      // c[f][p] = cos((2p+1) f pi/16), from dct_tensor
    __shared__ float matS[9];
    __shared__ float shiftS[3];
    __shared__ float coef[32 * 72]; // dequantized coeffs, stride 72/block (bank-friendly)
    __shared__ float pixY[16 * 128];
    __shared__ float pixCb[8 * 64];
    __shared__ float pixCr[8 * 64];

    const int tid = threadIdx.x;
    const int b  = blockIdx.z;   // batch
    const int th = blockIdx.y;   // tile row  0..127
    const int tw = blockIdx.x;   // tile col  0..15

    // ---- setup: tables ----
    if (tid < 64) {
        const float f = (float)factor_p[0];
        qY[tid] = y_table[tid] * f * alpha[tid];
        qC[tid] = c_table[tid] * f * alpha[tid];
        const int x = tid >> 3, u = tid & 7;
        // tensor[x,y,u,v] = c[x,u]*c[y,v]; c[0,*] = 1 -> c[x,u] = tensor[x,0,u,0]
        cosT[tid] = dct[x * 512 + u * 8];
    } else if (tid >= 64 && tid < 73) {
        matS[tid - 64] = matp[tid - 64];
    } else if (tid >= 73 && tid < 76) {
        shiftS[tid - 73] = shiftp[tid - 73];
    }
    __syncthreads();

    // ---- stage Y coeffs (32 blocks, dequantized) into LDS ----
    {
        // Y block rows 2*th, 2*th+1; block cols tw*16 .. tw*16+16
        const size_t base0 =
            (((size_t)b * (YBLK_COLS * (H / 8))) + (size_t)(2 * th) * YBLK_COLS + (size_t)tw * 16) * 64;
        const int flat = tid * 4;           // 0..1020
        const int within = flat & 63;
#pragma unroll
        for (int s = 0; s < 2; s++) {
            const float4 v4 = *(const float4*)(yg + base0 + (size_t)s * (YBLK_COLS * 64 / 4) * 0 + (size_t)s * 16384 + flat);
            const int blk = s * 16 + (flat >> 6);
            float4 w;
            w.x = v4.x * qY[within + 0];
            w.y = v4.y * qY[within + 1];
            w.z = v4.z * qY[within + 2];
            w.w = v4.w * qY[within + 3];
            *(float4*)&coef[blk * 72 + within] = w;
        }
    }
    __syncthreads();

    // ---- separable IDCT helper: thread owns one (block, v) column ----
    // out[u,v] = 0.25 * sum_x c[x,u] * (sum_y D[x,y] * c[y,v]) + 128
    auto idct8 = [&](const float* Dp, int v, float* p) {
        float cv[8];
#pragma unroll
        for (int yy = 0; yy < 8; yy++) cv[yy] = cosT[yy * 8 + v];
        float t[8];
#pragma unroll
        for (int x = 0; x < 8; x++) {
            const float4 a = *(const float4*)(Dp + x * 8);
            const float4 c = *(const float4*)(Dp + x * 8 + 4);
            t[x] = a.x * cv[0] + a.y * cv[1] + a.z * cv[2] + a.w * cv[3]
                 + c.x * cv[4] + c.y * cv[5] + c.z * cv[6] + c.w * cv[7];
        }
#pragma unroll
        for (int u = 0; u < 8; u++) {
            float s = 0.f;
#pragma unroll
            for (int x = 0; x < 8; x++) s += t[x] * cosT[x * 8 + u];
            p[u] = 0.25f * s + 128.0f;
        }
    };

    // ---- Y IDCT: 256 threads = 32 blocks x 8 v-columns ----
    {
        const int bh  = tid >> 7;       // 0..1
        const int rem = tid & 127;      // col within tile
        const int bw  = rem >> 3;       // 0..15
        const int v   = rem & 7;
        const float* Dp = &coef[(bh * 16 + bw) * 72];
        float p[8];
        idct8(Dp, v, p);
#pragma unroll
        for (int u = 0; u < 8; u++) pixY[(bh * 8 + u) * 128 + rem] = p[u];
    }
    __syncthreads();   // coef consumed; pixY ready

    // ---- stage chroma coeffs (8 Cb + 8 Cr blocks) ----
    {
        const int half = tid >> 7;           // 0 = Cb, 1 = Cr
        const int t    = tid & 127;
        const int flat = t * 4;              // 0..508
        const int within = flat & 63;
        const float* src = half ? crg : cbg;
        const size_t basec =
            (((size_t)b * (CBLK_COLS * (H / 16))) + (size_t)th * CBLK_COLS + (size_t)tw * 8) * 64;
        const float4 v4 = *(const float4*)(src + basec + flat);
        const int blk = half * 8 + (flat >> 6);
        float4 w;
        w.x = v4.x * qC[within + 0];
        w.y = v4.y * qC[within + 1];
        w.z = v4.z * qC[within + 2];
        w.w = v4.w * qC[within + 3];
        *(float4*)&coef[blk * 72 + within] = w;
    }
    __syncthreads();

    // ---- chroma IDCT: 128 threads = 16 blocks x 8 v-columns ----
    if (tid < 128) {
        const int blk = tid >> 3;     // 0..15 (0-7 Cb, 8-15 Cr)
        const int v   = tid & 7;
        const float* Dp = &coef[blk * 72];
        float p[8];
        idct8(Dp, v, p);
        float* dst = (blk >= 8) ? pixCr : pixCb;
        const int col = (blk & 7) * 8 + v;
#pragma unroll
        for (int u = 0; u < 8; u++) dst[u * 64 + col] = p[u];
    }
    __syncthreads();

    // ---- fused upsample + color convert + clip + store ----
    {
        const float s0 = shiftS[0], s1 = shiftS[1], s2 = shiftS[2];
        const float m0 = matS[0], m1 = matS[1], m2 = matS[2];
        const float m3 = matS[3], m4 = matS[4], m5 = matS[5];
        const float m6 = matS[6], m7 = matS[7], m8 = matS[8];
        const float inv255 = 1.0f / 255.0f;
        const size_t planeStride = (size_t)H * W;
        const size_t outBase = (size_t)b * 3 * planeStride;

#pragma unroll
        for (int it = 0; it < 2; it++) {
            const int idx = it * 256 + tid;     // 0..511
            const int r  = idx >> 5;            // 0..15
            const int c4 = (idx & 31) << 2;     // 0..124, step 4
            const float4 yv = *(const float4*)&pixY[r * 128 + c4];
            const int rc = r >> 1, cc = c4 >> 1;
            const float cb0 = pixCb[rc * 64 + cc + 0] + s1;
            const float cb1 = pixCb[rc * 64 + cc + 1] + s1;
            const float cr0 = pixCr[rc * 64 + cc + 0] + s2;
            const float cr1 = pixCr[rc * 64 + cc + 1] + s2;
            const float yy[4] = { yv.x + s0, yv.y + s0, yv.z + s0, yv.w + s0 };
            const float cbv[2] = { cb0, cb1 };
            const float crv[2] = { cr0, cr1 };

            float4 R, G, Bv;
            float* Rp = &R.x; float* Gp = &G.x; float* Bp = &Bv.x;
#pragma unroll
            for (int j = 0; j < 4; j++) {
                const int h2 = j >> 1;
                const float Yv = yy[j], Cb = cbv[h2], Cr = crv[h2];
                const float r_ = Yv * m0 + Cb * m3 + Cr * m6;
                const float g_ = Yv * m1 + Cb * m4 + Cr * m7;
                const float b_ = Yv * m2 + Cb * m5 + Cr * m8;
                Rp[j] = fminf(fmaxf(r_, 0.0f), 255.0f) * inv255;
                Gp[j] = fminf(fmaxf(g_, 0.0f), 255.0f) * inv255;
                Bp[j] = fminf(fmaxf(b_, 0.0f), 255.0f) * inv255;
            }

            const size_t row = (size_t)th * 16 + r;
            const size_t col = (size_t)tw * 128 + c4;
            const size_t o = outBase + row * W + col;
            *(float4*)(out + o)                  = R;
            *(float4*)(out + o + planeStride)    = G;
            *(float4*)(out + o + 2 * planeStride) = Bv;
        }
    }
}

extern "C" void kernel_launch(void* const* d_in, const int* in_sizes, int n_in,
                              void* d_out, int out_size, void* d_ws, size_t ws_size,
                              hipStream_t stream) {
    (void)in_sizes; (void)n_in; (void)d_ws; (void)ws_size; (void)out_size;
    const float* yg      = (const float*)d_in[0];
    const float* cbg     = (const float*)d_in[1];
    const float* crg     = (const float*)d_in[2];
    const float* y_table = (const float*)d_in[3];
    const float* c_table = (const float*)d_in[4];
    const float* alpha   = (const float*)d_in[5];
    const float* dct     = (const float*)d_in[6];
    const float* shiftp  = (const float*)d_in[7];
    const float* matp    = (const float*)d_in[8];
    const int*   factor  = (const int*)d_in[11];
    float* outp = (float*)d_out;

    dim3 grid(W / 128, H / 16, 8);   // (16, 128, 8)
    jpeg_decode_kernel<<<grid, 256, 0, stream>>>(
        yg, cbg, crg, y_table, c_table, alpha, dct, shiftp, matp, factor, outp);
}